// Round 8
// baseline (127.539 us; speedup 1.0000x reference)
//
#include <hip/hip_runtime.h>

// inputs: [M=4096, N=16384] fp32 logits; targets: [M] int32; k = int(0.01*(N-1)) = 163
#define M        4096
#define N        16384
#define K_SEL    163
#define DELTA_W  5.0f
#define NT       256
#define GRIDA    2048          // kernel A grid: 8 blocks/CU, 32 waves/CU
#define ITERS    32            // (M*N/4) / (GRIDA*NT) float4s per thread
#define SEGCAP   32            // slots per (row, wave-load) segment; mean 5.8, 8.5 sigma safe
#define SPR      64            // segments per row = (N/4)/64
#define SCALE    4096.0f       // fixed-point for hard-negative sum
#define GSCALE   1048576.0     // 2^20 fixed-point for the global row-loss sum
#define THRESH   2.0f          // E[count(x>=2)] = 373 per row; 11 sigma above K_SEL

typedef float vfloat4 __attribute__((ext_vector_type(4)));

// Order-preserving float<->uint32 key (ascending float <-> ascending key)
__device__ __forceinline__ unsigned f2key(float x) {
    unsigned u = __float_as_uint(x);
    return u ^ ((unsigned)((int)u >> 31) | 0x80000000u);
}
__device__ __forceinline__ float key2f(unsigned k) {
    unsigned u = k ^ (~(unsigned)((int)k >> 31) | 0x80000000u);
    return __uint_as_float(u);
}
__device__ __forceinline__ void wave_lgkm_wait() {
    asm volatile("s_waitcnt lgkmcnt(0)" ::: "memory");
}

// ---------- Kernel A: max-TLP grid-stride filter. No LDS, no barriers, no atomics. ----------
// Wave-load = 64 lanes x float4 = 1 KB contiguous, wave-uniform row & segment.
// Candidate slots assigned by ballot+mbcnt rank -> fixed global segment (deterministic).
__global__ __launch_bounds__(NT) void stream_candidates(
    const float* __restrict__ inp, const int* __restrict__ tgt,
    unsigned* __restrict__ hdr, unsigned* __restrict__ list,
    unsigned long long* __restrict__ acc)
{
    const int tid  = threadIdx.x;
    const int lane = tid & 63;
    if (blockIdx.x == 0 && tid == 0) *acc = 0ull;   // A precedes B in-stream: safe zero

    const vfloat4* p4 = reinterpret_cast<const vfloat4*>(inp);
    const unsigned gbase = blockIdx.x * NT + tid;

    #pragma unroll 4
    for (int it = 0; it < ITERS; ++it) {
        const unsigned g = (unsigned)it * (GRIDA * NT) + gbase;   // float4 index
        vfloat4 v = p4[g];
        const int row     = g >> 12;                 // wave-uniform
        const int target  = tgt[row];
        const int colbase = (g << 2) & (N - 1);

        bool pr[4];
        unsigned long long bal[4];
        #pragma unroll
        for (int j = 0; j < 4; ++j) {
            pr[j]  = (v[j] >= THRESH) && ((colbase + j) != target);
            bal[j] = __ballot(pr[j]);
        }
        const unsigned n0 = (unsigned)__popcll(bal[0]);
        const unsigned n1 = (unsigned)__popcll(bal[1]);
        const unsigned n2 = (unsigned)__popcll(bal[2]);
        const unsigned n3 = (unsigned)__popcll(bal[3]);
        const unsigned total = n0 + n1 + n2 + n3;

        if (total) {                                  // wave-uniform branch
            unsigned* seg = list + (size_t)(g >> 6) * SEGCAP;
            unsigned off = 0;
            #pragma unroll
            for (int j = 0; j < 4; ++j) {
                if (pr[j]) {
                    unsigned r = __builtin_amdgcn_mbcnt_hi(
                        (unsigned)(bal[j] >> 32),
                        __builtin_amdgcn_mbcnt_lo((unsigned)bal[j], 0u));
                    unsigned slot = off + r;
                    if (slot < SEGCAP) seg[slot] = f2key(v[j]);
                }
                off += (j == 0) ? n0 : (j == 1) ? n1 : (j == 2) ? n2 : n3;
            }
        }
        if (lane == 0) hdr[g >> 6] = total;           // TRUE count (overflow detectable)
    }
}

// ---------- Kernel B: wave-per-row radix select over segments, zero __syncthreads ----------
__global__ __launch_bounds__(NT) void select_and_loss(
    const float* __restrict__ inp, const int* __restrict__ tgt,
    const unsigned* __restrict__ hdr, const unsigned* __restrict__ list,
    unsigned long long* __restrict__ acc)
{
    __shared__ unsigned hist_all[4][256];    // wave-private 1 KiB each
    const int lane = threadIdx.x & 63;
    const int wv   = threadIdx.x >> 6;
    const int row  = blockIdx.x * 4 + wv;
    unsigned* hist = hist_all[wv];
    const float* rp = inp + (size_t)row * N;
    const int target = tgt[row];

    const unsigned n_l = hdr[row * SPR + lane];      // this lane's segment count
    unsigned csum = n_l;                             // wave total -> CHI
    #pragma unroll
    for (int off = 32; off > 0; off >>= 1) csum += __shfl_down(csum, off);
    const unsigned CHI = __shfl(csum, 0);
    const bool ovf = __any(n_l > SEGCAP);

    unsigned prefix = 0u, kr = K_SEL;
    float loss = 0.0f;
    bool have = false;

    if (!ovf && CHI >= K_SEL) {
        // ---- main path: each lane owns its segment's <=32 keys in registers ----
        const unsigned* seg = list + (size_t)(row * SPR + lane) * SEGCAP;
        unsigned keys[SEGCAP];
        #pragma unroll
        for (int i = 0; i < SEGCAP; ++i) keys[i] = (i < (int)n_l) ? seg[i] : 0u;

        for (int pass = 0; pass < 4; ++pass) {
            *reinterpret_cast<uint4*>(&hist[lane * 4]) = make_uint4(0, 0, 0, 0);
            wave_lgkm_wait();
            const int shift = 24 - 8 * pass;
            #pragma unroll
            for (int i = 0; i < SEGCAP; ++i) {
                unsigned k = keys[i];
                bool m = (i < (int)n_l) &&
                         (pass == 0 || (k >> (shift + 8)) == prefix);
                if (m) atomicAdd(&hist[(k >> shift) & 0xFFu], 1u);
            }
            wave_lgkm_wait();
            uint4 h = *reinterpret_cast<const uint4*>(&hist[lane * 4]);
            unsigned hb[4] = {h.x, h.y, h.z, h.w};
            unsigned s_local = hb[0] + hb[1] + hb[2] + hb[3];
            unsigned suf = s_local;                   // suffix-scan over lanes
            #pragma unroll
            for (int off = 1; off < 64; off <<= 1) {
                unsigned o = __shfl_down(suf, off);
                suf += (lane + off < 64) ? o : 0u;
            }
            unsigned acc_above = suf - s_local;
            int foundc = -1; unsigned f_abv = 0;
            #pragma unroll
            for (int c = 3; c >= 0; --c) {
                unsigned S = acc_above + hb[c];
                if (acc_above < kr && S >= kr) { foundc = c; f_abv = acc_above; }
                acc_above = S;
            }
            bool win = (foundc >= 0);
            unsigned long long bal = __ballot(win);
            int wl = __ffsll((long long)bal) - 1;
            unsigned np = win ? ((prefix << 8) | (unsigned)(lane * 4 + foundc)) : 0u;
            unsigned nk = win ? (kr - f_abv) : 0u;
            prefix = __shfl(np, wl);
            kr     = __shfl(nk, wl);
        }
        const unsigned tkey = prefix, krem = kr;

        int facc = 0;                                 // fixed-point, order-independent
        #pragma unroll
        for (int i = 0; i < SEGCAP; ++i) {
            unsigned k = keys[i];
            if (i < (int)n_l && k > tkey) {
                float w = key2f(k) + 1.0f;
                facc += (int)(w * w * SCALE + 0.5f);
            }
        }
        #pragma unroll
        for (int off = 32; off > 0; off >>= 1) facc += __shfl_down(facc, off);
        if (lane == 0) {
            float tv    = key2f(tkey) + 1.0f;
            float total = (float)facc * (1.0f / SCALE) + (float)krem * tv * tv;
            float pos   = rp[target];
            float pd    = pos - 1.0f;
            loss = DELTA_W * pd * pd + total * (1.0f / (float)K_SEL);
            have = true;
        }
    } else {
        // ---- fallback: exact full-row radix (never taken for Gaussian bench data) ----
        for (int pass = 0; pass < 4; ++pass) {
            *reinterpret_cast<uint4*>(&hist[lane * 4]) = make_uint4(0, 0, 0, 0);
            wave_lgkm_wait();
            const int shift = 24 - 8 * pass;
            for (int it = 0; it < N / 64; ++it) {
                int i = lane + it * 64;
                unsigned k = f2key(rp[i]);
                if (i == target) k = 0u;
                bool m = (pass == 0) || ((k >> (shift + 8)) == prefix);
                if (m) atomicAdd(&hist[(k >> shift) & 0xFFu], 1u);
            }
            wave_lgkm_wait();
            uint4 h = *reinterpret_cast<const uint4*>(&hist[lane * 4]);
            unsigned hb[4] = {h.x, h.y, h.z, h.w};
            unsigned s_local = hb[0] + hb[1] + hb[2] + hb[3];
            unsigned suf = s_local;
            #pragma unroll
            for (int off = 1; off < 64; off <<= 1) {
                unsigned o = __shfl_down(suf, off);
                suf += (lane + off < 64) ? o : 0u;
            }
            unsigned acc_above = suf - s_local;
            int foundc = -1; unsigned f_abv = 0;
            #pragma unroll
            for (int c = 3; c >= 0; --c) {
                unsigned S = acc_above + hb[c];
                if (acc_above < kr && S >= kr) { foundc = c; f_abv = acc_above; }
                acc_above = S;
            }
            bool win = (foundc >= 0);
            unsigned long long bal = __ballot(win);
            int wl = __ffsll((long long)bal) - 1;
            unsigned np = win ? ((prefix << 8) | (unsigned)(lane * 4 + foundc)) : 0u;
            unsigned nk = win ? (kr - f_abv) : 0u;
            prefix = __shfl(np, wl);
            kr     = __shfl(nk, wl);
        }
        const unsigned tkey = prefix, krem = kr;

        int facc = 0;
        for (int it = 0; it < N / 64; ++it) {
            int i = lane + it * 64;
            unsigned k = f2key(rp[i]);
            if (i == target) k = 0u;
            if (k > tkey) { float w = key2f(k) + 1.0f; facc += (int)(w * w * SCALE + 0.5f); }
        }
        #pragma unroll
        for (int off = 32; off > 0; off >>= 1) facc += __shfl_down(facc, off);
        if (lane == 0) {
            float tv    = key2f(tkey) + 1.0f;
            float total = (float)facc * (1.0f / SCALE) + (float)krem * tv * tv;
            float pos   = rp[target];
            float pd    = pos - 1.0f;
            loss = DELTA_W * pd * pd + total * (1.0f / (float)K_SEL);
            have = true;
        }
    }

    // deterministic global mean: 2^20 fixed-point integer accumulate (loss >= 0)
    if (have) {
        unsigned long long q = (unsigned long long)((double)loss * GSCALE + 0.5);
        atomicAdd(acc, q);
    }
}

__global__ void finalize(const unsigned long long* __restrict__ acc,
                         float* __restrict__ out)
{
    if (threadIdx.x == 0)
        out[0] = (float)((double)(*acc) / (GSCALE * (double)M));
}

extern "C" void kernel_launch(void* const* d_in, const int* in_sizes, int n_in,
                              void* d_out, int out_size, void* d_ws, size_t ws_size,
                              hipStream_t stream) {
    const float* inp = (const float*)d_in[0];
    const int*   tgt = (const int*)d_in[1];
    float* out = (float*)d_out;

    // ws layout: hdr (1 MiB) | list (32 MiB) | acc (8 B)
    unsigned* hdr  = (unsigned*)d_ws;
    unsigned* list = (unsigned*)((char*)d_ws + (size_t)M * SPR * 4);
    unsigned long long* acc =
        (unsigned long long*)((char*)d_ws + (size_t)M * SPR * 4
                              + (size_t)M * SPR * SEGCAP * 4);

    stream_candidates<<<GRIDA, NT, 0, stream>>>(inp, tgt, hdr, list, acc);
    select_and_loss<<<M / 4, NT, 0, stream>>>(inp, tgt, hdr, list, acc);
    finalize<<<1, 64, 0, stream>>>(acc, out);
}

// Round 9
// 124.158 us; speedup vs baseline: 1.0272x; 1.0272x over previous
//
#include <hip/hip_runtime.h>

// inputs: [M=4096, N=16384] fp32 logits; targets: [M] int32; k = int(0.01*(N-1)) = 163
#define M        4096
#define N        16384
#define K_SEL    163
#define DELTA_W  5.0f
#define NT       256
#define GRIDA    2048          // kernel A grid: 8 blocks/CU
#define ITERS    32            // (M*N/4) / (GRIDA*NT)
#define CAPW     512           // per-row LDS candidate list cap (mean 372, sd 19; 7.4 sigma)
#define SCALE    4096.0f       // fixed-point for hard-negative sum (order-independent)
#define GSCALE   1048576.0     // 2^20 fixed-point for the global row-loss sum
#define THRESH   2.0f          // E[count(x>=2)] = 373 per row; 11 sigma above K_SEL

typedef float vfloat4 __attribute__((ext_vector_type(4)));

// Order-preserving float<->uint32 key (ascending float <-> ascending key)
__device__ __forceinline__ unsigned f2key(float x) {
    unsigned u = __float_as_uint(x);
    return u ^ ((unsigned)((int)u >> 31) | 0x80000000u);
}
__device__ __forceinline__ float key2f(unsigned k) {
    unsigned u = k ^ (~(unsigned)((int)k >> 31) | 0x80000000u);
    return __uint_as_float(u);
}
__device__ __forceinline__ void wave_lgkm_wait() {
    asm volatile("s_waitcnt lgkmcnt(0)" ::: "memory");
}

// ---------- Kernel A: memcpy-class mask emitter. NO branches on data, no LDS, ----------
// ---------- no atomics, no per-element work. 1 KB read -> 32 B mask written.  ----------
// Mask layout: word (g>>6)*4+j, bit l  <->  element 4*(g & ~63u) + 4*l + j.
__global__ __launch_bounds__(NT) void stream_mask(
    const float* __restrict__ inp, unsigned long long* __restrict__ maskbuf,
    unsigned long long* __restrict__ acc)
{
    const int tid  = threadIdx.x;
    const int lane = tid & 63;
    if (blockIdx.x == 0 && tid == 0) *acc = 0ull;   // A precedes B in-stream

    const vfloat4* p4 = reinterpret_cast<const vfloat4*>(inp);
    const unsigned gbase = blockIdx.x * NT + tid;

    #pragma unroll 8
    for (int it = 0; it < ITERS; ++it) {
        const unsigned g = (unsigned)it * (GRIDA * NT) + gbase;   // float4 index
        vfloat4 v = p4[g];
        unsigned long long b0 = __ballot(v[0] >= THRESH);
        unsigned long long b1 = __ballot(v[1] >= THRESH);
        unsigned long long b2 = __ballot(v[2] >= THRESH);
        unsigned long long b3 = __ballot(v[3] >= THRESH);
        if (lane < 4) {                                           // 32 B per wave-load
            unsigned long long w = (lane == 0) ? b0 : (lane == 1) ? b1
                                 : (lane == 2) ? b2 : b3;
            maskbuf[(size_t)(g >> 6) * 4 + lane] = w;
        }
    }
}

// ---------- Kernel B: wave-per-row. Mask -> gather candidates -> LDS list ----------
// ---------- (deterministic prefix slots) -> proven radix select + loss.    ----------
__global__ __launch_bounds__(NT) void select_and_loss(
    const float* __restrict__ inp, const int* __restrict__ tgt,
    const unsigned long long* __restrict__ maskbuf,
    unsigned long long* __restrict__ acc)
{
    __shared__ unsigned hist_all[4][256];   // wave-private 1 KiB
    __shared__ unsigned list_all[4][CAPW];  // wave-private 2 KiB
    const int lane = threadIdx.x & 63;
    const int wv   = threadIdx.x >> 6;
    const int row  = blockIdx.x * 4 + wv;
    unsigned* hist = hist_all[wv];
    unsigned* list = list_all[wv];
    const float* rp = inp + (size_t)row * N;
    const int target = tgt[row];

    // lane l owns the row's l-th 256-element chunk: 4 mask words, 32 B consecutive
    const unsigned long long* mrow = maskbuf + (size_t)row * 256;
    unsigned long long w[4];
    #pragma unroll
    for (int j = 0; j < 4; ++j) w[j] = mrow[lane * 4 + j];

    // clear the positive's bit (element t: chunk t>>8, word t&3, bit (t&255)>>2)
    if ((target >> 8) == lane) {
        const int j = target & 3, b = (target & 255) >> 2;
        w[j] &= ~(1ull << b);
    }

    const unsigned myc = (unsigned)(__popcll(w[0]) + __popcll(w[1])
                                  + __popcll(w[2]) + __popcll(w[3]));
    unsigned inc = myc;                      // inclusive scan over lanes
    #pragma unroll
    for (int off = 1; off < 64; off <<= 1) {
        unsigned t = __shfl_up(inc, off);
        if (lane >= off) inc += t;
    }
    const unsigned C   = __shfl(inc, 63);    // row candidate count (exact)
    const unsigned pre = inc - myc;          // exclusive prefix -> deterministic slots

    unsigned prefix = 0u, kr = K_SEL;
    float loss = 0.0f;
    bool have = false;

    if (C >= K_SEL && C <= CAPW) {
        // gather candidates into wave-private LDS list at fixed positions
        unsigned pos = pre;
        #pragma unroll
        for (int j = 0; j < 4; ++j) {
            unsigned long long m = w[j];
            while (m) {
                const int b = __builtin_ctzll(m); m &= m - 1;
                const int idx = lane * 256 + b * 4 + j;
                list[pos++] = f2key(rp[idx]);
            }
        }
        wave_lgkm_wait();

        unsigned keys[8];
        #pragma unroll
        for (int it = 0; it < 8; ++it) {
            const unsigned i = lane + it * 64u;
            keys[it] = (i < C) ? list[i] : 0u;     // pad with min-key
        }
        for (int pass = 0; pass < 4; ++pass) {
            *reinterpret_cast<uint4*>(&hist[lane * 4]) = make_uint4(0, 0, 0, 0);
            wave_lgkm_wait();
            const int shift = 24 - 8 * pass;
            #pragma unroll
            for (int it = 0; it < 8; ++it) {
                unsigned k = keys[it];
                bool mm = (lane + it * 64u < C) &&
                          (pass == 0 || (k >> (shift + 8)) == prefix);
                if (mm) atomicAdd(&hist[(k >> shift) & 0xFFu], 1u);
            }
            wave_lgkm_wait();
            uint4 h = *reinterpret_cast<const uint4*>(&hist[lane * 4]);
            unsigned hb[4] = {h.x, h.y, h.z, h.w};
            unsigned s_local = hb[0] + hb[1] + hb[2] + hb[3];
            unsigned suf = s_local;                // suffix-scan over lanes
            #pragma unroll
            for (int off = 1; off < 64; off <<= 1) {
                unsigned o = __shfl_down(suf, off);
                suf += (lane + off < 64) ? o : 0u;
            }
            unsigned acc_above = suf - s_local;
            int foundc = -1; unsigned f_abv = 0;
            #pragma unroll
            for (int c = 3; c >= 0; --c) {
                unsigned S = acc_above + hb[c];
                if (acc_above < kr && S >= kr) { foundc = c; f_abv = acc_above; }
                acc_above = S;
            }
            bool win = (foundc >= 0);
            unsigned long long bal = __ballot(win);
            int wl = __ffsll((long long)bal) - 1;
            unsigned np = win ? ((prefix << 8) | (unsigned)(lane * 4 + foundc)) : 0u;
            unsigned nk = win ? (kr - f_abv) : 0u;
            prefix = __shfl(np, wl);
            kr     = __shfl(nk, wl);
        }
        const unsigned tkey = prefix, krem = kr;

        int facc = 0;                              // fixed-point, order-independent
        #pragma unroll
        for (int it = 0; it < 8; ++it) {
            unsigned k = keys[it];
            if ((lane + it * 64u) < C && k > tkey) {
                float ww = key2f(k) + 1.0f;
                facc += (int)(ww * ww * SCALE + 0.5f);
            }
        }
        #pragma unroll
        for (int off = 32; off > 0; off >>= 1) facc += __shfl_down(facc, off);
        if (lane == 0) {
            float tv    = key2f(tkey) + 1.0f;
            float total = (float)facc * (1.0f / SCALE) + (float)krem * tv * tv;
            float pd    = rp[target] - 1.0f;
            loss = DELTA_W * pd * pd + total * (1.0f / (float)K_SEL);
            have = true;
        }
    } else {
        // fallback: exact full-row radix (never taken for Gaussian bench data)
        for (int pass = 0; pass < 4; ++pass) {
            *reinterpret_cast<uint4*>(&hist[lane * 4]) = make_uint4(0, 0, 0, 0);
            wave_lgkm_wait();
            const int shift = 24 - 8 * pass;
            for (int it = 0; it < N / 64; ++it) {
                int i = lane + it * 64;
                unsigned k = f2key(rp[i]);
                if (i == target) k = 0u;
                bool mm = (pass == 0) || ((k >> (shift + 8)) == prefix);
                if (mm) atomicAdd(&hist[(k >> shift) & 0xFFu], 1u);
            }
            wave_lgkm_wait();
            uint4 h = *reinterpret_cast<const uint4*>(&hist[lane * 4]);
            unsigned hb[4] = {h.x, h.y, h.z, h.w};
            unsigned s_local = hb[0] + hb[1] + hb[2] + hb[3];
            unsigned suf = s_local;
            #pragma unroll
            for (int off = 1; off < 64; off <<= 1) {
                unsigned o = __shfl_down(suf, off);
                suf += (lane + off < 64) ? o : 0u;
            }
            unsigned acc_above = suf - s_local;
            int foundc = -1; unsigned f_abv = 0;
            #pragma unroll
            for (int c = 3; c >= 0; --c) {
                unsigned S = acc_above + hb[c];
                if (acc_above < kr && S >= kr) { foundc = c; f_abv = acc_above; }
                acc_above = S;
            }
            bool win = (foundc >= 0);
            unsigned long long bal = __ballot(win);
            int wl = __ffsll((long long)bal) - 1;
            unsigned np = win ? ((prefix << 8) | (unsigned)(lane * 4 + foundc)) : 0u;
            unsigned nk = win ? (kr - f_abv) : 0u;
            prefix = __shfl(np, wl);
            kr     = __shfl(nk, wl);
        }
        const unsigned tkey = prefix, krem = kr;

        int facc = 0;
        for (int it = 0; it < N / 64; ++it) {
            int i = lane + it * 64;
            unsigned k = f2key(rp[i]);
            if (i == target) k = 0u;
            if (k > tkey) { float ww = key2f(k) + 1.0f; facc += (int)(ww * ww * SCALE + 0.5f); }
        }
        #pragma unroll
        for (int off = 32; off > 0; off >>= 1) facc += __shfl_down(facc, off);
        if (lane == 0) {
            float tv    = key2f(tkey) + 1.0f;
            float total = (float)facc * (1.0f / SCALE) + (float)krem * tv * tv;
            float pd    = rp[target] - 1.0f;
            loss = DELTA_W * pd * pd + total * (1.0f / (float)K_SEL);
            have = true;
        }
    }

    // deterministic global mean: 2^20 fixed-point integer accumulate (loss >= 0)
    if (have) {
        unsigned long long q = (unsigned long long)((double)loss * GSCALE + 0.5);
        atomicAdd(acc, q);
    }
}

__global__ void finalize(const unsigned long long* __restrict__ acc,
                         float* __restrict__ out)
{
    if (threadIdx.x == 0)
        out[0] = (float)((double)(*acc) / (GSCALE * (double)M));
}

extern "C" void kernel_launch(void* const* d_in, const int* in_sizes, int n_in,
                              void* d_out, int out_size, void* d_ws, size_t ws_size,
                              hipStream_t stream) {
    const float* inp = (const float*)d_in[0];
    const int*   tgt = (const int*)d_in[1];
    float* out = (float*)d_out;

    // ws layout: maskbuf (8 MiB) | acc (8 B)
    unsigned long long* maskbuf = (unsigned long long*)d_ws;
    unsigned long long* acc =
        (unsigned long long*)((char*)d_ws + (size_t)(M / 256) * N * 4 * 8);

    stream_mask<<<GRIDA, NT, 0, stream>>>(inp, maskbuf, acc);
    select_and_loss<<<M / 4, NT, 0, stream>>>(inp, tgt, maskbuf, acc);
    finalize<<<1, 64, 0, stream>>>(acc, out);
}